// Round 2
// baseline (426.109 us; speedup 1.0000x reference)
//
#include <hip/hip_runtime.h>

#define B_TOTAL 16384
#define D 128
#define NROWS 27          // 1 dense + 26 sparse
#define BT 16             // batch elements per block
#define DC 16             // D-chunk in floats
#define NCHUNK (D / DC)   // 8
#define NSTRIDE 260       // floats per LDS row: 16 elems * 16 f32 + 4 pad (odd granule stride)
#define LDSROWS 30        // 27 real + 3 garbage pad rows (group 4 = rows 24..29)
#define OUTC 506          // 128 + 378

__global__ __launch_bounds__(256, 4)
void dotint_kernel(const float* __restrict__ dense,
                   const float* __restrict__ sparse,
                   float* __restrict__ out)
{
    __shared__ float lds[LDSROWS * NSTRIDE];

    const int tid = threadIdx.x;
    const int b0  = blockIdx.x * BT;
    const int e   = tid >> 4;        // element 0..15 (4 per wave)
    const int s   = tid & 15;        // sub-thread (pair-tile) 0..15

    // tile (gi,gj) from sub index: 15 lower-tri tiles of the 5x5 group grid
    const int sc = (s < 15) ? s : 14;          // s==15 duplicates tile 14, never stored
    const int gi = (sc >= 1) + (sc >= 3) + (sc >= 6) + (sc >= 10);
    const int gj = sc - ((gi * (gi + 1)) >> 1);
    const int i0 = 6 * gi;
    const int j0 = 6 * gj;

    // staging lane decode: lane -> (element, lds q-slot); swizzle on global source
    const int lane = tid & 63;
    const int wave = tid >> 6;
    const int se   = lane >> 2;                // 0..15
    const int sq   = lane & 3;                 // lds 16B slot within element
    const int sdc4 = sq ^ (se & 3);            // global dc4 stored at slot sq

    // ---- dense passthrough: out[b][0:128] = dense[b]  (float2: rows are 8B-aligned)
    #pragma unroll
    for (int r = 0; r < 4; ++r) {
        int idx = tid + r * 256;               // 0..1023 float2-index
        int ee  = idx >> 6;
        int dd  = idx & 63;
        const float2 v = *reinterpret_cast<const float2*>(
            dense + (size_t)(b0 + ee) * D + dd * 2);
        *reinterpret_cast<float2*>(
            out + (size_t)(b0 + ee) * OUTC + dd * 2) = v;
    }

    float acc[6][6];
    #pragma unroll
    for (int a = 0; a < 6; ++a)
        #pragma unroll
        for (int b = 0; b < 6; ++b) acc[a][b] = 0.f;

    #pragma unroll 1
    for (int c = 0; c < NCHUNK; ++c) {
        const int dc0 = c * DC;
        // ---- stage chunk: wave w loads rows n = w, w+4, ... (wave-uniform LDS base)
        for (int n = wave; n < NROWS; n += 4) {
            const float* srcbase = (n == 0)
                ? dense
                : sparse + (size_t)(n - 1) * (size_t)B_TOTAL * D;
            const float* src = srcbase + (size_t)(b0 + se) * D + dc0 + sdc4 * 4;
            __builtin_amdgcn_global_load_lds(
                (const __attribute__((address_space(1))) void*)src,
                (__attribute__((address_space(3))) void*)&lds[n * NSTRIDE],
                16, 0, 0);
        }
        __syncthreads();   // drains vmcnt before barrier (compiler-inserted)

        // ---- compute: 4 float4 sub-steps; 12 ds_read_b128 + 144 FMA each
        #pragma unroll
        for (int q = 0; q < 4; ++q) {
            const int slot = q ^ (e & 3);      // undo source-side swizzle
            float4 ri[6], rj[6];
            #pragma unroll
            for (int k = 0; k < 6; ++k)
                ri[k] = *reinterpret_cast<const float4*>(
                    &lds[(i0 + k) * NSTRIDE + e * 16 + slot * 4]);
            #pragma unroll
            for (int k = 0; k < 6; ++k)
                rj[k] = *reinterpret_cast<const float4*>(
                    &lds[(j0 + k) * NSTRIDE + e * 16 + slot * 4]);
            #pragma unroll
            for (int a = 0; a < 6; ++a)
                #pragma unroll
                for (int b = 0; b < 6; ++b) {
                    acc[a][b] = fmaf(ri[a].x, rj[b].x, acc[a][b]);
                    acc[a][b] = fmaf(ri[a].y, rj[b].y, acc[a][b]);
                    acc[a][b] = fmaf(ri[a].z, rj[b].z, acc[a][b]);
                    acc[a][b] = fmaf(ri[a].w, rj[b].w, acc[a][b]);
                }
        }
        __syncthreads();   // protect LDS before next chunk's staging
    }

    // ---- store lower-triangle results: out[b][128 + i*(i+1)/2 + j]
    if (s < 15) {
        float* orow = out + (size_t)(b0 + e) * OUTC + D;
        #pragma unroll
        for (int a = 0; a < 6; ++a) {
            const int i = i0 + a;
            if (i < NROWS) {
                const int ibase = (i * (i + 1)) >> 1;
                #pragma unroll
                for (int b = 0; b < 6; ++b) {
                    const int j = j0 + b;
                    if (j < NROWS && j <= i) orow[ibase + j] = acc[a][b];
                }
            }
        }
    }
}

extern "C" void kernel_launch(void* const* d_in, const int* in_sizes, int n_in,
                              void* d_out, int out_size, void* d_ws, size_t ws_size,
                              hipStream_t stream)
{
    const float* dense  = (const float*)d_in[0];
    const float* sparse = (const float*)d_in[1];
    float* out          = (float*)d_out;

    dim3 grid(B_TOTAL / BT);   // 1024 blocks = 4 per CU
    dim3 block(256);
    hipLaunchKernelGGL(dotint_kernel, grid, block, 0, stream, dense, sparse, out);
}

// Round 3
// 336.987 us; speedup vs baseline: 1.2645x; 1.2645x over previous
//
#include <hip/hip_runtime.h>

#define B_TOTAL 16384
#define D 128
#define NROWS 27            // 1 dense + 26 sparse
#define BT 16               // batch elements per block
#define DC 32               // D-chunk in floats = 128B = one cache line per row-elem
#define NCHUNK (D / DC)     // 4
#define NSTRIDE 524         // dwords per LDS row: 16 elems * 32 f32 + 12 pad (bank spread)
#define LDSROWS 30          // 27 real + 3 garbage pad rows (group 4 = rows 24..29)
#define OSTRIDE 386         // dwords per element in lds_out tri buffer (378 used, even, ≡2 mod 32)
#define OUTC 506            // 128 + 378

__global__ __launch_bounds__(256, 2)
void dotint_kernel(const float* __restrict__ dense,
                   const float* __restrict__ sparse,
                   float* __restrict__ out)
{
    // union: staging buffer (30*524 = 15720 dw) reused as tri-out buffer (16*386 = 6176 dw)
    __shared__ float lds[LDSROWS * NSTRIDE];

    const int tid = threadIdx.x;
    const int b0  = blockIdx.x * BT;
    const int e   = tid >> 4;        // element 0..15 (4 per wave)
    const int s   = tid & 15;        // sub-thread (pair-tile) 0..15

    // 15 lower-tri tiles of the 5x5 group grid (6-row groups, rows 27..29 pad)
    const int sc = (s < 15) ? s : 14;          // s==15 duplicates tile 14, never stored
    const int gi = (sc >= 1) + (sc >= 3) + (sc >= 6) + (sc >= 10);
    const int gj = sc - ((gi * (gi + 1)) >> 1);
    const int i0 = 6 * gi;
    const int j0 = 6 * gj;

    // staging lane decode: one wave-instruction covers 8 elements x 32 floats (1KB)
    const int lane = tid & 63;
    const int wave = tid >> 6;
    const int sq   = lane & 7;                 // 16B slot within element block
    const int seh  = lane >> 3;                // element-within-half 0..7

    const int eswz = e & 7;                    // read-side slot swizzle key

    float acc[6][6];
    #pragma unroll
    for (int a = 0; a < 6; ++a)
        #pragma unroll
        for (int b = 0; b < 6; ++b) acc[a][b] = 0.f;

    #pragma unroll 1
    for (int c = 0; c < NCHUNK; ++c) {
        const int dc0 = c * DC;
        // ---- stage chunk: 27 rows x 2 half-rows; instruction r2 -> (row n, half h)
        for (int r2 = wave; r2 < NROWS * 2; r2 += 4) {
            const int n = r2 >> 1;
            const int h = r2 & 1;
            const int el = h * 8 + seh;        // element 0..15
            const float* srcbase = (n == 0)
                ? dense
                : sparse + (size_t)(n - 1) * (size_t)B_TOTAL * D;
            // XOR slot swizzle applied on the GLOBAL source (rule #21)
            const float* src = srcbase + (size_t)(b0 + el) * D + dc0
                             + (size_t)((sq ^ (el & 7)) * 4);
            __builtin_amdgcn_global_load_lds(
                (const __attribute__((address_space(1))) void*)src,
                (__attribute__((address_space(3))) void*)&lds[n * NSTRIDE + h * 256],
                16, 0, 0);
        }
        __syncthreads();   // drains vmcnt (compiler-inserted) before reads

        // ---- compute: 8 float4 sub-steps; 12 ds_read_b128 + 144 FMA each
        #pragma unroll
        for (int q = 0; q < 8; ++q) {
            const int slot = (q ^ eswz) * 4;   // undo source-side swizzle
            float4 ri[6], rj[6];
            #pragma unroll
            for (int k = 0; k < 6; ++k)
                ri[k] = *reinterpret_cast<const float4*>(
                    &lds[(i0 + k) * NSTRIDE + e * 32 + slot]);
            #pragma unroll
            for (int k = 0; k < 6; ++k)
                rj[k] = *reinterpret_cast<const float4*>(
                    &lds[(j0 + k) * NSTRIDE + e * 32 + slot]);
            #pragma unroll
            for (int a = 0; a < 6; ++a)
                #pragma unroll
                for (int b = 0; b < 6; ++b) {
                    acc[a][b] = fmaf(ri[a].x, rj[b].x, acc[a][b]);
                    acc[a][b] = fmaf(ri[a].y, rj[b].y, acc[a][b]);
                    acc[a][b] = fmaf(ri[a].z, rj[b].z, acc[a][b]);
                    acc[a][b] = fmaf(ri[a].w, rj[b].w, acc[a][b]);
                }
        }
        __syncthreads();   // protect LDS before next chunk's staging
    }

    // ---- tri results -> LDS (scattered dwords, cheap), then coalesced global write
    if (s < 15) {
        #pragma unroll
        for (int a = 0; a < 6; ++a) {
            const int i = i0 + a;
            if (i < NROWS) {
                const int ibase = (i * (i + 1)) >> 1;
                #pragma unroll
                for (int b = 0; b < 6; ++b) {
                    const int j = j0 + b;
                    if (j < NROWS && j <= i)
                        lds[e * OSTRIDE + ibase + j] = acc[a][b];
                }
            }
        }
    }
    __syncthreads();

    // block's output region: 16 rows x 506 f32 = 4048 float2, contiguous in memory
    float* oblk = out + (size_t)b0 * OUTC;
    #pragma unroll
    for (int k = 0; k < 16; ++k) {
        const int f2 = tid + k * 256;          // float2 index 0..4047
        if (f2 < 8 * OUTC) {
            const int b = f2 / 253;            // = (2*f2)/506, magic-mul
            const int cc = 2 * f2 - b * OUTC;  // 0..504, even; never straddles row/dense boundary
            float2 v;
            if (cc < D) {
                v = *reinterpret_cast<const float2*>(dense + (size_t)(b0 + b) * D + cc);
            } else {
                v = *reinterpret_cast<const float2*>(&lds[b * OSTRIDE + (cc - D)]);
            }
            *reinterpret_cast<float2*>(oblk + (size_t)b * OUTC + cc) = v;
        }
    }
}

extern "C" void kernel_launch(void* const* d_in, const int* in_sizes, int n_in,
                              void* d_out, int out_size, void* d_ws, size_t ws_size,
                              hipStream_t stream)
{
    const float* dense  = (const float*)d_in[0];
    const float* sparse = (const float*)d_in[1];
    float* out          = (float*)d_out;

    dim3 grid(B_TOTAL / BT);   // 1024 blocks = 2 resident per CU (LDS-limited)
    dim3 block(256);
    hipLaunchKernelGGL(dotint_kernel, grid, block, 0, stream, dense, sparse, out);
}